// Round 1
// baseline (864.489 us; speedup 1.0000x reference)
//
#include <hip/hip_runtime.h>
#include <hip/hip_bf16.h>

typedef __attribute__((ext_vector_type(4))) float f32x4;
typedef __attribute__((ext_vector_type(8))) short bf16x8;

#define NR 12288
#define HD 256
#define TAU 0.5f

__device__ __forceinline__ unsigned short f2bf(float f) {
    unsigned int x = __builtin_bit_cast(unsigned int, f);
    x += 0x7fffu + ((x >> 16) & 1u);
    return (unsigned short)(x >> 16);
}

// ---------- cast f32 -> bf16 (4 elems/thread) ----------
__global__ __launch_bounds__(256) void cast4_kernel(const float* __restrict__ src,
                                                    unsigned short* __restrict__ dst, int n4) {
    int i = blockIdx.x * 256 + threadIdx.x;
    if (i >= n4) return;
    float4 v = ((const float4*)src)[i];
    ushort4 u;
    u.x = f2bf(v.x); u.y = f2bf(v.y); u.z = f2bf(v.z); u.w = f2bf(v.w);
    ((ushort4*)dst)[i] = u;
}

// ---------- W[k][n] f32 -> Wt[n][k] bf16 ----------
__global__ __launch_bounds__(256) void transpose_cast_kernel(const float* __restrict__ W,
                                                             unsigned short* __restrict__ Wt) {
    int n = blockIdx.x;
    int k = threadIdx.x;
    Wt[n * HD + k] = f2bf(W[k * HD + n]);
}

// ---------- projection GEMM: C[M,256] = A[M,256] @ Bt[256,256]^T (+bias, opt elu) ----------
// A bf16 rows, Bt bf16 rows (Bt[n][k] = B[k][n]).  ELU=1: out bf16 elu;  ELU=0: out f32.
template <int ELU>
__global__ __launch_bounds__(256) void proj_kernel(const unsigned short* __restrict__ A,
                                                   const unsigned short* __restrict__ Bt,
                                                   const float* __restrict__ bias,
                                                   void* __restrict__ Cout) {
    const int lane = threadIdx.x & 63;
    const int wave = threadIdx.x >> 6;          // 0..3 -> 64-col group
    const int row0 = blockIdx.x * 64;
    const int col0 = wave * 64;
    const int lr = lane & 15, lk = lane >> 4;

    f32x4 acc[4][4] = {};
    const unsigned short* Ab = A + (size_t)(row0 + lr) * HD + lk * 8;
    const unsigned short* Bb = Bt + (size_t)(col0 + lr) * HD + lk * 8;
#pragma unroll
    for (int k0 = 0; k0 < HD; k0 += 32) {
        bf16x8 af[4], bfr[4];
#pragma unroll
        for (int m = 0; m < 4; ++m) af[m] = *(const bf16x8*)(Ab + m * 16 * HD + k0);
#pragma unroll
        for (int n = 0; n < 4; ++n) bfr[n] = *(const bf16x8*)(Bb + n * 16 * HD + k0);
#pragma unroll
        for (int m = 0; m < 4; ++m)
#pragma unroll
            for (int n = 0; n < 4; ++n)
                acc[m][n] = __builtin_amdgcn_mfma_f32_16x16x32_bf16(af[m], bfr[n], acc[m][n], 0, 0, 0);
    }
#pragma unroll
    for (int m = 0; m < 4; ++m) {
#pragma unroll
        for (int n = 0; n < 4; ++n) {
            int col = col0 + n * 16 + lr;
            float b = bias[col];
#pragma unroll
            for (int r = 0; r < 4; ++r) {
                int row = row0 + m * 16 + lk * 4 + r;
                float v = acc[m][n][r] + b;
                if (ELU) {
                    v = v > 0.f ? v : expm1f(v);
                    ((unsigned short*)Cout)[(size_t)row * HD + col] = f2bf(v);
                } else {
                    ((float*)Cout)[(size_t)row * HD + col] = v;
                }
            }
        }
    }
}

// ---------- normalize rows (fp32) -> bf16, plus fp32 diag dot / tau ----------
__global__ __launch_bounds__(256) void norm_diag_kernel(const float* __restrict__ h1,
                                                        const float* __restrict__ h2,
                                                        unsigned short* __restrict__ n1,
                                                        unsigned short* __restrict__ n2,
                                                        float* __restrict__ dvec) {
    const int lane = threadIdx.x & 63;
    const int wave = threadIdx.x >> 6;
    const int row = blockIdx.x * 4 + wave;
    const float4 a = *(const float4*)(h1 + (size_t)row * HD + lane * 4);
    const float4 b = *(const float4*)(h2 + (size_t)row * HD + lane * 4);
    float sa = a.x * a.x + a.y * a.y + a.z * a.z + a.w * a.w;
    float sb = b.x * b.x + b.y * b.y + b.z * b.z + b.w * b.w;
    float sab = a.x * b.x + a.y * b.y + a.z * b.z + a.w * b.w;
#pragma unroll
    for (int m = 32; m; m >>= 1) {
        sa += __shfl_xor(sa, m);
        sb += __shfl_xor(sb, m);
        sab += __shfl_xor(sab, m);
    }
    float na = sqrtf(sa); na = na > 1e-12f ? na : 1e-12f;
    float nb = sqrtf(sb); nb = nb > 1e-12f ? nb : 1e-12f;
    float ia = 1.f / na, ib = 1.f / nb;
    ushort4 u1, u2;
    u1.x = f2bf(a.x * ia); u1.y = f2bf(a.y * ia); u1.z = f2bf(a.z * ia); u1.w = f2bf(a.w * ia);
    u2.x = f2bf(b.x * ib); u2.y = f2bf(b.y * ib); u2.z = f2bf(b.z * ib); u2.w = f2bf(b.w * ib);
    *(ushort4*)(n1 + (size_t)row * HD + lane * 4) = u1;
    *(ushort4*)(n2 + (size_t)row * HD + lane * 4) = u2;
    if (lane == 0) dvec[row] = sab * ia * ib * (1.f / TAU);
}

// ---------- similarity tile: rowsum(exp(X@Y^T/tau)) [+ colsum] ----------
__global__ __launch_bounds__(256) void sim_kernel(const unsigned short* __restrict__ X,
                                                  const unsigned short* __restrict__ Y,
                                                  float* __restrict__ rowsum,
                                                  float* __restrict__ colsum) {
    const int lane = threadIdx.x & 63;
    const int wave = threadIdx.x >> 6;
    const int wr = wave >> 1, wc = wave & 1;    // 2x2 wave grid, 64x64 each
    const int r0 = blockIdx.x * 128 + wr * 64;
    const int c0 = blockIdx.y * 128 + wc * 64;
    const int lr = lane & 15, lk = lane >> 4;

    f32x4 acc[4][4] = {};
    const unsigned short* Xb = X + (size_t)(r0 + lr) * HD + lk * 8;
    const unsigned short* Yb = Y + (size_t)(c0 + lr) * HD + lk * 8;
#pragma unroll
    for (int k0 = 0; k0 < HD; k0 += 32) {
        bf16x8 af[4], bfr[4];
#pragma unroll
        for (int m = 0; m < 4; ++m) af[m] = *(const bf16x8*)(Xb + m * 16 * HD + k0);
#pragma unroll
        for (int n = 0; n < 4; ++n) bfr[n] = *(const bf16x8*)(Yb + n * 16 * HD + k0);
#pragma unroll
        for (int m = 0; m < 4; ++m)
#pragma unroll
            for (int n = 0; n < 4; ++n)
                acc[m][n] = __builtin_amdgcn_mfma_f32_16x16x32_bf16(af[m], bfr[n], acc[m][n], 0, 0, 0);
    }

    const float kexp = 2.8853901f;  // log2(e)/tau
    float e[4][4][4];
#pragma unroll
    for (int m = 0; m < 4; ++m)
#pragma unroll
        for (int n = 0; n < 4; ++n)
#pragma unroll
            for (int r = 0; r < 4; ++r)
                e[m][n][r] = exp2f(acc[m][n][r] * kexp);

    // row sums over this wave's 64 cols; frag value (m,n,r): row=r0+m*16+lk*4+r, col=c0+n*16+lr
#pragma unroll
    for (int m = 0; m < 4; ++m) {
        float rs[4];
#pragma unroll
        for (int r = 0; r < 4; ++r) {
            rs[r] = e[m][0][r] + e[m][1][r] + e[m][2][r] + e[m][3][r];
            rs[r] += __shfl_xor(rs[r], 1);
            rs[r] += __shfl_xor(rs[r], 2);
            rs[r] += __shfl_xor(rs[r], 4);
            rs[r] += __shfl_xor(rs[r], 8);
        }
        if (lr == 0) {
#pragma unroll
            for (int r = 0; r < 4; ++r) atomicAdd(&rowsum[r0 + m * 16 + lk * 4 + r], rs[r]);
        }
    }
    if (colsum) {
#pragma unroll
        for (int n = 0; n < 4; ++n) {
            float cs = 0.f;
#pragma unroll
            for (int m = 0; m < 4; ++m)
#pragma unroll
                for (int r = 0; r < 4; ++r) cs += e[m][n][r];
            cs += __shfl_xor(cs, 16);
            cs += __shfl_xor(cs, 32);
            if (lk == 0) atomicAdd(&colsum[c0 + n * 16 + lr], cs);
        }
    }
}

// ---------- loss ----------
__global__ __launch_bounds__(128) void loss_partial_kernel(const float* __restrict__ R1,
                                                           const float* __restrict__ B1,
                                                           const float* __restrict__ R2,
                                                           const float* __restrict__ B2,
                                                           const float* __restrict__ dvec,
                                                           float* __restrict__ partial) {
    int i = blockIdx.x * 128 + threadIdx.x;
    const float e2 = 7.389056099f;  // exp(1/tau)
    float d = dvec[i];
    float l1 = logf(R1[i] + B1[i] - e2) - d;
    float l2 = logf(R2[i] + B2[i] - e2) - d;
    float v = 0.5f * (l1 + l2);
#pragma unroll
    for (int m = 32; m; m >>= 1) v += __shfl_xor(v, m);
    __shared__ float wsum[2];
    if ((threadIdx.x & 63) == 0) wsum[threadIdx.x >> 6] = v;
    __syncthreads();
    if (threadIdx.x == 0) partial[blockIdx.x] = wsum[0] + wsum[1];
}

__global__ __launch_bounds__(128) void loss_final_kernel(const float* __restrict__ partial,
                                                         float* __restrict__ out, int nb) {
    float s = 0.f;
    for (int i = threadIdx.x; i < nb; i += 128) s += partial[i];
#pragma unroll
    for (int m = 32; m; m >>= 1) s += __shfl_xor(s, m);
    __shared__ float wsum[2];
    if ((threadIdx.x & 63) == 0) wsum[threadIdx.x >> 6] = s;
    __syncthreads();
    if (threadIdx.x == 0) out[0] = (wsum[0] + wsum[1]) * (1.f / (float)NR);
}

extern "C" void kernel_launch(void* const* d_in, const int* in_sizes, int n_in,
                              void* d_out, int out_size, void* d_ws, size_t ws_size,
                              hipStream_t stream) {
    const float* z1 = (const float*)d_in[0];
    const float* z2 = (const float*)d_in[1];
    const float* W1 = (const float*)d_in[2];
    const float* b1 = (const float*)d_in[3];
    const float* W2 = (const float*)d_in[4];
    const float* b2 = (const float*)d_in[5];

    char* ws = (char*)d_ws;
    size_t off = 0;
    auto alloc = [&](size_t bytes) {
        void* p = ws + off;
        off += (bytes + 255) & ~(size_t)255;
        return p;
    };
    const size_t NH2 = (size_t)NR * HD * 2;  // bf16 matrix bytes
    unsigned short* zb1 = (unsigned short*)alloc(NH2);
    unsigned short* zb2 = (unsigned short*)alloc(NH2);
    unsigned short* W1t = (unsigned short*)alloc(HD * HD * 2);
    unsigned short* W2t = (unsigned short*)alloc(HD * HD * 2);
    unsigned short* t1 = (unsigned short*)alloc(NH2);
    unsigned short* t2 = (unsigned short*)alloc(NH2);
    float* h1 = (float*)alloc((size_t)NR * HD * 4);
    float* h2 = (float*)alloc((size_t)NR * HD * 4);
    unsigned short* n1 = (unsigned short*)alloc(NH2);
    unsigned short* n2 = (unsigned short*)alloc(NH2);
    float* R1 = (float*)alloc(NR * 4);
    float* B1 = (float*)alloc(NR * 4);
    float* B2 = (float*)alloc(NR * 4);
    float* R2 = (float*)alloc(NR * 4);
    float* dvec = (float*)alloc(NR * 4);
    float* partial = (float*)alloc(96 * 4);

    const int n4 = NR * HD / 4;
    cast4_kernel<<<(n4 + 255) / 256, 256, 0, stream>>>(z1, zb1, n4);
    cast4_kernel<<<(n4 + 255) / 256, 256, 0, stream>>>(z2, zb2, n4);
    transpose_cast_kernel<<<HD, 256, 0, stream>>>(W1, W1t);
    transpose_cast_kernel<<<HD, 256, 0, stream>>>(W2, W2t);

    proj_kernel<1><<<NR / 64, 256, 0, stream>>>(zb1, W1t, b1, t1);
    proj_kernel<1><<<NR / 64, 256, 0, stream>>>(zb2, W1t, b1, t2);
    proj_kernel<0><<<NR / 64, 256, 0, stream>>>(t1, W2t, b2, h1);
    proj_kernel<0><<<NR / 64, 256, 0, stream>>>(t2, W2t, b2, h2);

    norm_diag_kernel<<<NR / 4, 256, 0, stream>>>(h1, h2, n1, n2, dvec);

    hipMemsetAsync(R1, 0, (size_t)NR * 4 * 4, stream);  // R1,B1,B2,R2 contiguous

    dim3 simgrid(NR / 128, NR / 128);
    sim_kernel<<<simgrid, 256, 0, stream>>>(n1, n1, R1, nullptr);
    sim_kernel<<<simgrid, 256, 0, stream>>>(n1, n2, B1, B2);
    sim_kernel<<<simgrid, 256, 0, stream>>>(n2, n2, R2, nullptr);

    loss_partial_kernel<<<NR / 128, 128, 0, stream>>>(R1, B1, R2, B2, dvec, partial);
    loss_final_kernel<<<1, 128, 0, stream>>>(partial, (float*)d_out, NR / 128);
}

// Round 2
// 437.493 us; speedup vs baseline: 1.9760x; 1.9760x over previous
//
#include <hip/hip_runtime.h>
#include <hip/hip_bf16.h>

typedef __attribute__((ext_vector_type(4))) float f32x4;
typedef __attribute__((ext_vector_type(8))) short bf16x8;

#define NR 12288
#define HD 256
#define TAU 0.5f
#define NT 96                 // 128-row tiles per dim
#define NTRI (NT * (NT + 1) / 2)

__device__ __forceinline__ unsigned short f2bf(float f) {
    unsigned int x = __builtin_bit_cast(unsigned int, f);
    x += 0x7fffu + ((x >> 16) & 1u);
    return (unsigned short)(x >> 16);
}

// ---------- cast f32 -> bf16 (4 elems/thread) ----------
__global__ __launch_bounds__(256) void cast4_kernel(const float* __restrict__ src,
                                                    unsigned short* __restrict__ dst, int n4) {
    int i = blockIdx.x * 256 + threadIdx.x;
    if (i >= n4) return;
    float4 v = ((const float4*)src)[i];
    ushort4 u;
    u.x = f2bf(v.x); u.y = f2bf(v.y); u.z = f2bf(v.z); u.w = f2bf(v.w);
    ((ushort4*)dst)[i] = u;
}

// ---------- W[k][n] f32 -> Wt[n][k] bf16 ----------
__global__ __launch_bounds__(256) void transpose_cast_kernel(const float* __restrict__ W,
                                                             unsigned short* __restrict__ Wt) {
    int n = blockIdx.x;
    int k = threadIdx.x;
    Wt[n * HD + k] = f2bf(W[k * HD + n]);
}

// ---------- projection GEMM: C[M,256] = A[M,256] @ Bt[256,256]^T (+bias, opt elu) ----------
template <int ELU>
__global__ __launch_bounds__(256) void proj_kernel(const unsigned short* __restrict__ A,
                                                   const unsigned short* __restrict__ Bt,
                                                   const float* __restrict__ bias,
                                                   void* __restrict__ Cout) {
    const int lane = threadIdx.x & 63;
    const int wave = threadIdx.x >> 6;
    const int row0 = blockIdx.x * 64;
    const int col0 = wave * 64;
    const int lr = lane & 15, lk = lane >> 4;

    f32x4 acc[4][4] = {};
    const unsigned short* Ab = A + (size_t)(row0 + lr) * HD + lk * 8;
    const unsigned short* Bb = Bt + (size_t)(col0 + lr) * HD + lk * 8;
#pragma unroll
    for (int k0 = 0; k0 < HD; k0 += 32) {
        bf16x8 af[4], bfr[4];
#pragma unroll
        for (int m = 0; m < 4; ++m) af[m] = *(const bf16x8*)(Ab + m * 16 * HD + k0);
#pragma unroll
        for (int n = 0; n < 4; ++n) bfr[n] = *(const bf16x8*)(Bb + n * 16 * HD + k0);
#pragma unroll
        for (int m = 0; m < 4; ++m)
#pragma unroll
            for (int n = 0; n < 4; ++n)
                acc[m][n] = __builtin_amdgcn_mfma_f32_16x16x32_bf16(af[m], bfr[n], acc[m][n], 0, 0, 0);
    }
#pragma unroll
    for (int m = 0; m < 4; ++m) {
#pragma unroll
        for (int n = 0; n < 4; ++n) {
            int col = col0 + n * 16 + lr;
            float b = bias[col];
#pragma unroll
            for (int r = 0; r < 4; ++r) {
                int row = row0 + m * 16 + lk * 4 + r;
                float v = acc[m][n][r] + b;
                if (ELU) {
                    v = v > 0.f ? v : expm1f(v);
                    ((unsigned short*)Cout)[(size_t)row * HD + col] = f2bf(v);
                } else {
                    ((float*)Cout)[(size_t)row * HD + col] = v;
                }
            }
        }
    }
}

// ---------- normalize rows (fp32) -> bf16, plus fp32 diag dot / tau ----------
__global__ __launch_bounds__(256) void norm_diag_kernel(const float* __restrict__ h1,
                                                        const float* __restrict__ h2,
                                                        unsigned short* __restrict__ n1,
                                                        unsigned short* __restrict__ n2,
                                                        float* __restrict__ dvec) {
    const int lane = threadIdx.x & 63;
    const int wave = threadIdx.x >> 6;
    const int row = blockIdx.x * 4 + wave;
    const float4 a = *(const float4*)(h1 + (size_t)row * HD + lane * 4);
    const float4 b = *(const float4*)(h2 + (size_t)row * HD + lane * 4);
    float sa = a.x * a.x + a.y * a.y + a.z * a.z + a.w * a.w;
    float sb = b.x * b.x + b.y * b.y + b.z * b.z + b.w * b.w;
    float sab = a.x * b.x + a.y * b.y + a.z * b.z + a.w * b.w;
#pragma unroll
    for (int m = 32; m; m >>= 1) {
        sa += __shfl_xor(sa, m);
        sb += __shfl_xor(sb, m);
        sab += __shfl_xor(sab, m);
    }
    float na = sqrtf(sa); na = na > 1e-12f ? na : 1e-12f;
    float nb = sqrtf(sb); nb = nb > 1e-12f ? nb : 1e-12f;
    float ia = 1.f / na, ib = 1.f / nb;
    ushort4 u1, u2;
    u1.x = f2bf(a.x * ia); u1.y = f2bf(a.y * ia); u1.z = f2bf(a.z * ia); u1.w = f2bf(a.w * ia);
    u2.x = f2bf(b.x * ib); u2.y = f2bf(b.y * ib); u2.z = f2bf(b.z * ib); u2.w = f2bf(b.w * ib);
    *(ushort4*)(n1 + (size_t)row * HD + lane * 4) = u1;
    *(ushort4*)(n2 + (size_t)row * HD + lane * 4) = u2;
    if (lane == 0) dvec[row] = sab * ia * ib * (1.f / TAU);
}

// ---------- fused similarity: all 3 Gram products, symmetric refl scheduled upper-tri ----------
// Tasks: [0,NTRI)        refl1 tile (i<=j) of n1@n1^T : rowsum->R1[i-rows], colsum->R1[j-rows] (i<j)
//        [NTRI,2*NTRI)   refl2 same with n2 -> R2
//        [2*NTRI, +NT*NT) between n1@n2^T full grid : rowsum->B1, colsum->B2
__global__ __launch_bounds__(256) void sim_fused_kernel(const unsigned short* __restrict__ n1v,
                                                        const unsigned short* __restrict__ n2v,
                                                        float* __restrict__ R1,
                                                        float* __restrict__ R2,
                                                        float* __restrict__ B1,
                                                        float* __restrict__ B2) {
    __shared__ __align__(16) unsigned short lA[128 * 64];  // 16KB
    __shared__ __align__(16) unsigned short lB[128 * 64];  // 16KB

    const int b = blockIdx.x;
    const unsigned short* X;
    const unsigned short* Y;
    float* rowp;
    float* colp;
    int ti, tj;
    bool diag = false;
    if (b < 2 * NTRI) {
        int p = (b >= NTRI) ? 1 : 0;
        int t = b - p * NTRI;
        int i = (int)((193.f - sqrtf((float)(193 * 193 - 8 * t))) * 0.5f);
        if (i < 0) i = 0;
        if (i > NT - 1) i = NT - 1;
        while (i > 0 && i * NT - i * (i - 1) / 2 > t) --i;
        while ((i + 1) * NT - (i + 1) * i / 2 <= t) ++i;
        int j = i + (t - (i * NT - i * (i - 1) / 2));
        ti = i; tj = j;
        X = p ? n2v : n1v;
        Y = X;
        rowp = p ? R2 : R1;
        diag = (i == j);
        colp = diag ? nullptr : rowp;
    } else {
        int t = b - 2 * NTRI;
        ti = t / NT; tj = t % NT;
        X = n1v; Y = n2v;
        rowp = B1; colp = B2;
    }
    const int r0 = ti * 128, c0 = tj * 128;

    const int t = threadIdx.x;
    const int lane = t & 63, wave = t >> 6;
    const int wr = wave >> 1, wc = wave & 1;
    const int lr = lane & 15, lk = lane >> 4;

    f32x4 acc[4][4] = {};

    // staging: chunk idx = c*256 + t covers 16B each; row = idx>>3, col = (idx&7)*8
    const int srow = t >> 3, scol = (t & 7) * 8;

#pragma unroll
    for (int kt = 0; kt < 4; ++kt) {
        __syncthreads();
        const int k0 = kt * 64;
#pragma unroll
        for (int c = 0; c < 4; ++c) {
            const unsigned short* ga = X + (size_t)(r0 + c * 32 + srow) * HD + k0 + scol;
            __builtin_amdgcn_global_load_lds(
                (const __attribute__((address_space(1))) unsigned int*)ga,
                (__attribute__((address_space(3))) unsigned int*)(lA + (c * 4 + wave) * 512),
                16, 0, 0);
        }
        if (!diag) {
#pragma unroll
            for (int c = 0; c < 4; ++c) {
                const unsigned short* gb = Y + (size_t)(c0 + c * 32 + srow) * HD + k0 + scol;
                __builtin_amdgcn_global_load_lds(
                    (const __attribute__((address_space(1))) unsigned int*)gb,
                    (__attribute__((address_space(3))) unsigned int*)(lB + (c * 4 + wave) * 512),
                    16, 0, 0);
            }
        }
        __syncthreads();
        const unsigned short* sB = diag ? lA : lB;
#pragma unroll
        for (int ks = 0; ks < 2; ++ks) {
            bf16x8 af[4], bfr[4];
#pragma unroll
            for (int m = 0; m < 4; ++m)
                af[m] = *(const bf16x8*)(lA + (wr * 64 + m * 16 + lr) * 64 + ks * 32 + lk * 8);
#pragma unroll
            for (int n = 0; n < 4; ++n)
                bfr[n] = *(const bf16x8*)(sB + (wc * 64 + n * 16 + lr) * 64 + ks * 32 + lk * 8);
#pragma unroll
            for (int m = 0; m < 4; ++m)
#pragma unroll
                for (int n = 0; n < 4; ++n)
                    acc[m][n] = __builtin_amdgcn_mfma_f32_16x16x32_bf16(af[m], bfr[n], acc[m][n], 0, 0, 0);
        }
    }

    const float kexp = 2.8853901f;  // log2(e)/tau
    float e[4][4][4];
#pragma unroll
    for (int m = 0; m < 4; ++m)
#pragma unroll
        for (int n = 0; n < 4; ++n)
#pragma unroll
            for (int r = 0; r < 4; ++r)
                e[m][n][r] = exp2f(acc[m][n][r] * kexp);

    // rowsum: value (m,n,r): row = r0 + wr*64 + m*16 + lk*4 + r, col = c0 + wc*64 + n*16 + lr
#pragma unroll
    for (int m = 0; m < 4; ++m) {
        float rs[4];
#pragma unroll
        for (int r = 0; r < 4; ++r) {
            rs[r] = e[m][0][r] + e[m][1][r] + e[m][2][r] + e[m][3][r];
            rs[r] += __shfl_xor(rs[r], 1);
            rs[r] += __shfl_xor(rs[r], 2);
            rs[r] += __shfl_xor(rs[r], 4);
            rs[r] += __shfl_xor(rs[r], 8);
        }
        if (lr == 0) {
#pragma unroll
            for (int r = 0; r < 4; ++r)
                atomicAdd(&rowp[r0 + wr * 64 + m * 16 + lk * 4 + r], rs[r]);
        }
    }
    if (colp) {
#pragma unroll
        for (int n = 0; n < 4; ++n) {
            float cs = 0.f;
#pragma unroll
            for (int m = 0; m < 4; ++m)
#pragma unroll
                for (int r = 0; r < 4; ++r) cs += e[m][n][r];
            cs += __shfl_xor(cs, 16);
            cs += __shfl_xor(cs, 32);
            if (lk == 0) atomicAdd(&colp[c0 + wc * 64 + n * 16 + lr], cs);
        }
    }
}

// ---------- loss ----------
__global__ __launch_bounds__(128) void loss_partial_kernel(const float* __restrict__ R1,
                                                           const float* __restrict__ B1,
                                                           const float* __restrict__ R2,
                                                           const float* __restrict__ B2,
                                                           const float* __restrict__ dvec,
                                                           float* __restrict__ partial) {
    int i = blockIdx.x * 128 + threadIdx.x;
    const float e2 = 7.389056099f;  // exp(1/tau)
    float d = dvec[i];
    float l1 = logf(R1[i] + B1[i] - e2) - d;
    float l2 = logf(R2[i] + B2[i] - e2) - d;
    float v = 0.5f * (l1 + l2);
#pragma unroll
    for (int m = 32; m; m >>= 1) v += __shfl_xor(v, m);
    __shared__ float wsum[2];
    if ((threadIdx.x & 63) == 0) wsum[threadIdx.x >> 6] = v;
    __syncthreads();
    if (threadIdx.x == 0) partial[blockIdx.x] = wsum[0] + wsum[1];
}

__global__ __launch_bounds__(128) void loss_final_kernel(const float* __restrict__ partial,
                                                         float* __restrict__ out, int nb) {
    float s = 0.f;
    for (int i = threadIdx.x; i < nb; i += 128) s += partial[i];
#pragma unroll
    for (int m = 32; m; m >>= 1) s += __shfl_xor(s, m);
    __shared__ float wsum[2];
    if ((threadIdx.x & 63) == 0) wsum[threadIdx.x >> 6] = s;
    __syncthreads();
    if (threadIdx.x == 0) out[0] = (wsum[0] + wsum[1]) * (1.f / (float)NR);
}

extern "C" void kernel_launch(void* const* d_in, const int* in_sizes, int n_in,
                              void* d_out, int out_size, void* d_ws, size_t ws_size,
                              hipStream_t stream) {
    const float* z1 = (const float*)d_in[0];
    const float* z2 = (const float*)d_in[1];
    const float* W1 = (const float*)d_in[2];
    const float* b1 = (const float*)d_in[3];
    const float* W2 = (const float*)d_in[4];
    const float* b2 = (const float*)d_in[5];

    char* ws = (char*)d_ws;
    size_t off = 0;
    auto alloc = [&](size_t bytes) {
        void* p = ws + off;
        off += (bytes + 255) & ~(size_t)255;
        return p;
    };
    const size_t NH2 = (size_t)NR * HD * 2;  // bf16 matrix bytes
    unsigned short* zb1 = (unsigned short*)alloc(NH2);
    unsigned short* zb2 = (unsigned short*)alloc(NH2);
    unsigned short* W1t = (unsigned short*)alloc(HD * HD * 2);
    unsigned short* W2t = (unsigned short*)alloc(HD * HD * 2);
    unsigned short* t1 = (unsigned short*)alloc(NH2);
    unsigned short* t2 = (unsigned short*)alloc(NH2);
    float* h1 = (float*)alloc((size_t)NR * HD * 4);
    float* h2 = (float*)alloc((size_t)NR * HD * 4);
    unsigned short* n1 = (unsigned short*)alloc(NH2);
    unsigned short* n2 = (unsigned short*)alloc(NH2);
    float* R1 = (float*)alloc(NR * 4);
    float* B1 = (float*)alloc(NR * 4);
    float* B2 = (float*)alloc(NR * 4);
    float* R2 = (float*)alloc(NR * 4);
    float* dvec = (float*)alloc(NR * 4);
    float* partial = (float*)alloc(96 * 4);

    const int n4 = NR * HD / 4;
    cast4_kernel<<<(n4 + 255) / 256, 256, 0, stream>>>(z1, zb1, n4);
    cast4_kernel<<<(n4 + 255) / 256, 256, 0, stream>>>(z2, zb2, n4);
    transpose_cast_kernel<<<HD, 256, 0, stream>>>(W1, W1t);
    transpose_cast_kernel<<<HD, 256, 0, stream>>>(W2, W2t);

    proj_kernel<1><<<NR / 64, 256, 0, stream>>>(zb1, W1t, b1, t1);
    proj_kernel<1><<<NR / 64, 256, 0, stream>>>(zb2, W1t, b1, t2);
    proj_kernel<0><<<NR / 64, 256, 0, stream>>>(t1, W2t, b2, h1);
    proj_kernel<0><<<NR / 64, 256, 0, stream>>>(t2, W2t, b2, h2);

    norm_diag_kernel<<<NR / 4, 256, 0, stream>>>(h1, h2, n1, n2, dvec);

    hipMemsetAsync(R1, 0, (size_t)NR * 4 * 4, stream);  // R1,B1,B2,R2 contiguous

    sim_fused_kernel<<<2 * NTRI + NT * NT, 256, 0, stream>>>(n1, n2, R1, R2, B1, B2);

    loss_partial_kernel<<<NR / 128, 128, 0, stream>>>(R1, B1, R2, B2, dvec, partial);
    loss_final_kernel<<<1, 128, 0, stream>>>(partial, (float*)d_out, NR / 128);
}